// Round 1
// baseline (1399.786 us; speedup 1.0000x reference)
//
#include <hip/hip_runtime.h>
#include <math.h>

// Problem constants (B=8, N=2048, D=256, H=8, Dh=32)
#define BATCH 8
#define SEQ   2048
#define DIM   256
#define NHEAD 8
#define DHEAD 32
#define MROWS (BATCH*SEQ)   // 16384

// ---------------------------------------------------------------------------
// GEMM: C[M,Nc] = A[M,K] @ W[K,Nc] + bias, with epilogue modes:
//   MODE 0: plain store to C
//   MODE 1: relu store to C
//   MODE 2: qkv scatter  (c<256 -> qb +=, c<512 -> kb +=, else vb store)
//   MODE 3: pos scatter  (c<256 -> qb store, else kb store)
// Tile: BM=128, BN=128, BK=16, 256 threads, 8x8 per thread.
// ---------------------------------------------------------------------------
#define BM 128
#define BN 128
#define BK 16

template<int MODE>
__global__ __launch_bounds__(256) void gemm_kernel(
    const float* __restrict__ A, const float* __restrict__ W,
    const float* __restrict__ bias, float* __restrict__ C,
    int M, int K, int Nc,
    float* __restrict__ qb, float* __restrict__ kb, float* __restrict__ vb)
{
    __shared__ float As[BK][BM + 4];   // pad 132: scatter-write ~2-way, reads broadcast
    __shared__ float Bs[BK][BN];       // stride 128: 2-way on reads (free)

    const int t  = threadIdx.x;
    const int tx = t & 15;
    const int ty = t >> 4;
    const int r0 = blockIdx.y * BM;
    const int c0 = blockIdx.x * BN;

    float acc[8][8];
    #pragma unroll
    for (int i = 0; i < 8; ++i)
        #pragma unroll
        for (int j = 0; j < 8; ++j) acc[i][j] = 0.f;

    for (int k0 = 0; k0 < K; k0 += BK) {
        // --- stage A tile (128 x 16), transposed into As[kk][m] ---
        #pragma unroll
        for (int i = 0; i < 2; ++i) {
            int f  = t + i * 256;          // 0..511
            int m  = f >> 2;               // 0..127
            int kk = (f & 3) * 4;          // 0,4,8,12
            float4 av = *(const float4*)&A[(size_t)(r0 + m) * K + k0 + kk];
            As[kk + 0][m] = av.x; As[kk + 1][m] = av.y;
            As[kk + 2][m] = av.z; As[kk + 3][m] = av.w;
        }
        // --- stage B tile (16 x 128) ---
        #pragma unroll
        for (int i = 0; i < 2; ++i) {
            int f  = t + i * 256;
            int kk = f >> 5;               // 0..15
            int n  = (f & 31) * 4;         // 0..124
            *(float4*)&Bs[kk][n] =
                *(const float4*)&W[(size_t)(k0 + kk) * Nc + c0 + n];
        }
        __syncthreads();

        #pragma unroll
        for (int kk = 0; kk < BK; ++kk) {
            float a[8], b[8];
            *(float4*)&a[0] = *(const float4*)&As[kk][ty * 4];
            *(float4*)&a[4] = *(const float4*)&As[kk][64 + ty * 4];
            *(float4*)&b[0] = *(const float4*)&Bs[kk][tx * 4];
            *(float4*)&b[4] = *(const float4*)&Bs[kk][64 + tx * 4];
            #pragma unroll
            for (int i = 0; i < 8; ++i)
                #pragma unroll
                for (int j = 0; j < 8; ++j)
                    acc[i][j] += a[i] * b[j];
        }
        __syncthreads();
    }

    // --- epilogue ---
    #pragma unroll
    for (int ii = 0; ii < 8; ++ii) {
        int r = r0 + ((ii < 4) ? (ty * 4 + ii) : (64 + ty * 4 + ii - 4));
        #pragma unroll
        for (int ch = 0; ch < 2; ++ch) {
            int c = c0 + ch * 64 + tx * 4;
            float4 v;
            v.x = acc[ii][ch * 4 + 0] + bias[c + 0];
            v.y = acc[ii][ch * 4 + 1] + bias[c + 1];
            v.z = acc[ii][ch * 4 + 2] + bias[c + 2];
            v.w = acc[ii][ch * 4 + 3] + bias[c + 3];

            if (MODE == 0) {
                *(float4*)&C[(size_t)r * Nc + c] = v;
            } else if (MODE == 1) {
                v.x = fmaxf(v.x, 0.f); v.y = fmaxf(v.y, 0.f);
                v.z = fmaxf(v.z, 0.f); v.w = fmaxf(v.w, 0.f);
                *(float4*)&C[(size_t)r * Nc + c] = v;
            } else {
                // scatter into [B,H,N,Dh] buffers
                int bb = r >> 11;          // r / SEQ
                int n  = r & (SEQ - 1);
                int which = c >> 8;        // 0:q 1:k 2:v (pos: 0:q 1:k)
                int d  = c & 255;
                int hh = d >> 5;
                int dh = d & 31;
                size_t dst = (((size_t)bb * NHEAD + hh) * SEQ + n) * DHEAD + dh;
                if (MODE == 3) {           // pos projection: plain store
                    float* buf = (which == 0) ? qb : kb;
                    *(float4*)&buf[dst] = v;
                } else {                   // qkv: q,k accumulate onto pos; v store
                    if (which == 2) {
                        *(float4*)&vb[dst] = v;
                    } else {
                        float* buf = (which == 0) ? qb : kb;
                        float4 old = *(float4*)&buf[dst];
                        old.x += v.x; old.y += v.y; old.z += v.z; old.w += v.w;
                        *(float4*)&buf[dst] = old;
                    }
                }
            }
        }
    }
}

// ---------------------------------------------------------------------------
// Flash attention: one block = (b, h, 32 q-rows). 256 threads = 32 rows x 8.
// K/V streamed in 64-key tiles through LDS. Online softmax, wave-parallel
// reductions over the 8 lanes of each row (shfl_xor 1,2,4).
// Thread (r = t/8, g = t%8): scores for keys j = g + 8*jj (strided -> float4
// LDS reads conflict-free with pad 36); output dims d = g*4..g*4+3.
// ---------------------------------------------------------------------------
__global__ __launch_bounds__(256) void attn_kernel(
    const float* __restrict__ Q, const float* __restrict__ K,
    const float* __restrict__ V, const int* __restrict__ mask,
    float* __restrict__ O)
{
    __shared__ float ks[64][36];   // pad 36: conflict-free float4 reads (strided j)
    __shared__ float vs[64][32];   // j uniform in PV -> broadcast, no pad needed
    __shared__ float sc[32][68];   // probs; pad 68: conflict-free across rows

    const int t   = threadIdx.x;
    const int bid = blockIdx.x;            // ((b*H + h) * 64 + qt)
    const int qt  = bid & 63;
    const int bh  = bid >> 6;              // 0..63
    const int bb  = bh >> 3;
    const int hh  = bh & 7;
    const int q0  = qt * 32;

    const float* Qb = Q + (size_t)bh * SEQ * DHEAD;
    const float* Kb = K + (size_t)bh * SEQ * DHEAD;
    const float* Vb = V + (size_t)bh * SEQ * DHEAD;
    const int* mrow = mask + bb * SEQ;

    const int r = t >> 3;
    const int g = t & 7;
    const float scale = 0.17677669529663687f;   // 1/sqrt(32)

    // Q row into registers, pre-scaled
    float4 q4[8];
    #pragma unroll
    for (int dq = 0; dq < 8; ++dq) {
        float4 qv = *(const float4*)&Qb[(size_t)(q0 + r) * DHEAD + dq * 4];
        qv.x *= scale; qv.y *= scale; qv.z *= scale; qv.w *= scale;
        q4[dq] = qv;
    }

    float m = -1e30f, l = 0.f;
    float4 o = {0.f, 0.f, 0.f, 0.f};

    for (int kt = 0; kt < SEQ / 64; ++kt) {
        const int k0 = kt * 64;
        __syncthreads();   // previous tile's readers done before overwrite
        #pragma unroll
        for (int i = 0; i < 2; ++i) {
            int f  = (t + i * 256) * 4;    // 0..2044
            int rr = f >> 5;               // 0..63
            int dd = f & 31;
            *(float4*)&ks[rr][dd] = *(const float4*)&Kb[(size_t)(k0 + rr) * DHEAD + dd];
            *(float4*)&vs[rr][dd] = *(const float4*)&Vb[(size_t)(k0 + rr) * DHEAD + dd];
        }
        __syncthreads();

        // ---- scores: 8 keys per thread, j = g + 8*jj ----
        float s[8];
        #pragma unroll
        for (int jj = 0; jj < 8; ++jj) s[jj] = 0.f;
        #pragma unroll
        for (int dq = 0; dq < 8; ++dq) {
            float4 qv = q4[dq];
            #pragma unroll
            for (int jj = 0; jj < 8; ++jj) {
                float4 kv = *(const float4*)&ks[g + 8 * jj][dq * 4];
                s[jj] += qv.x * kv.x + qv.y * kv.y + qv.z * kv.z + qv.w * kv.w;
            }
        }
        #pragma unroll
        for (int jj = 0; jj < 8; ++jj)
            if (mrow[k0 + g + 8 * jj]) s[jj] = -1e30f;

        // ---- online softmax update (reduce over the row's 8 lanes) ----
        float tm = s[0];
        #pragma unroll
        for (int jj = 1; jj < 8; ++jj) tm = fmaxf(tm, s[jj]);
        tm = fmaxf(tm, __shfl_xor(tm, 1));
        tm = fmaxf(tm, __shfl_xor(tm, 2));
        tm = fmaxf(tm, __shfl_xor(tm, 4));
        float nm = fmaxf(m, tm);
        float pz = (nm <= -1e29f) ? 0.f : 1.f;   // all-masked-so-far guard
        float factor = __expf(m - nm) * ((m <= -1e29f) ? 0.f : 1.f) + ((m <= -1e29f) ? 1.f : 0.f) * 0.f;
        factor = (m <= -1e29f) ? 0.f : __expf(m - nm);
        float tl = 0.f;
        #pragma unroll
        for (int jj = 0; jj < 8; ++jj) {
            float p = __expf(s[jj] - nm) * pz;
            sc[r][g + 8 * jj] = p;
            tl += p;
        }
        tl += __shfl_xor(tl, 1);
        tl += __shfl_xor(tl, 2);
        tl += __shfl_xor(tl, 4);
        l = l * factor + tl;
        m = nm;
        o.x *= factor; o.y *= factor; o.z *= factor; o.w *= factor;

        __syncthreads();   // sc visible (also orders vs. next staging)

        // ---- PV: thread accumulates dims g*4..g*4+3 over all 64 keys ----
        #pragma unroll
        for (int jj4 = 0; jj4 < 16; ++jj4) {
            float4 pp = *(const float4*)&sc[r][jj4 * 4];
            float pr[4] = {pp.x, pp.y, pp.z, pp.w};
            #pragma unroll
            for (int u = 0; u < 4; ++u) {
                int j = jj4 * 4 + u;
                float4 vv = *(const float4*)&vs[j][g * 4];
                o.x += pr[u] * vv.x; o.y += pr[u] * vv.y;
                o.z += pr[u] * vv.z; o.w += pr[u] * vv.w;
            }
        }
    }

    const float inv = 1.f / l;
    float4 res;
    res.x = o.x * inv; res.y = o.y * inv; res.z = o.z * inv; res.w = o.w * inv;
    size_t orow = ((size_t)bb * SEQ + q0 + r) * DIM + hh * DHEAD + g * 4;
    *(float4*)&O[orow] = res;
}

// ---------------------------------------------------------------------------
// Fused residual + LayerNorm: one block = one 256-wide row.
// y = (v - mu) * rsqrt(var + eps) * g + b,  v = X[row] + R[row]
// ---------------------------------------------------------------------------
__global__ __launch_bounds__(256) void ln_kernel(
    const float* __restrict__ X, const float* __restrict__ R,
    const float* __restrict__ gam, const float* __restrict__ bet,
    float* __restrict__ Y)
{
    const int row = blockIdx.x;
    const int t   = threadIdx.x;
    __shared__ float wsum[4];
    __shared__ float mu_s, rs_s;

    float v = X[(size_t)row * DIM + t] + R[(size_t)row * DIM + t];

    float s = v;
    #pragma unroll
    for (int off = 1; off < 64; off <<= 1) s += __shfl_xor(s, off);
    const int w = t >> 6, lane = t & 63;
    if (lane == 0) wsum[w] = s;
    __syncthreads();
    if (t == 0) mu_s = (wsum[0] + wsum[1] + wsum[2] + wsum[3]) * (1.f / 256.f);
    __syncthreads();
    const float mu = mu_s;
    const float d  = v - mu;

    float s2 = d * d;
    #pragma unroll
    for (int off = 1; off < 64; off <<= 1) s2 += __shfl_xor(s2, off);
    if (lane == 0) wsum[w] = s2;
    __syncthreads();
    if (t == 0)
        rs_s = rsqrtf((wsum[0] + wsum[1] + wsum[2] + wsum[3]) * (1.f / 256.f) + 1e-5f);
    __syncthreads();

    Y[(size_t)row * DIM + t] = d * rs_s * gam[t] + bet[t];
}

// ---------------------------------------------------------------------------
extern "C" void kernel_launch(void* const* d_in, const int* in_sizes, int n_in,
                              void* d_out, int out_size, void* d_ws, size_t ws_size,
                              hipStream_t stream)
{
    const float* x    = (const float*)d_in[0];
    const float* pos  = (const float*)d_in[1];
    const int*   mask = (const int*)d_in[2];   // bool in jax; assuming int32 on device
    const float* Wqkv = (const float*)d_in[3];
    const float* bqkv = (const float*)d_in[4];
    const float* Wpos = (const float*)d_in[5];
    const float* bpos = (const float*)d_in[6];
    const float* ln1g = (const float*)d_in[7];
    const float* ln1b = (const float*)d_in[8];
    const float* W1   = (const float*)d_in[9];
    const float* b1   = (const float*)d_in[10];
    const float* W2   = (const float*)d_in[11];
    const float* b2   = (const float*)d_in[12];
    const float* ln2g = (const float*)d_in[13];
    const float* ln2b = (const float*)d_in[14];
    float* out = (float*)d_out;

    // workspace layout (floats); tmp aliases [qb..ao] (dead after ln1)
    float* ws   = (float*)d_ws;
    const size_t SZ = (size_t)MROWS * DIM;     // 4,194,304
    float* qb   = ws;
    float* kb   = qb + SZ;
    float* vb   = kb + SZ;
    float* ao   = vb + SZ;
    float* hbuf = ao + SZ;
    float* f2   = hbuf + SZ;
    float* tmp  = ws;                          // 16.78M floats, aliases qb..ao

    dim3 blk(256);

    // 1) pos @ Wpos + bpos -> scatter q_pos, k_pos
    gemm_kernel<3><<<dim3(512 / BN, MROWS / BM), blk, 0, stream>>>(
        pos, Wpos, bpos, nullptr, MROWS, 512, 512, qb, kb, nullptr);
    // 2) x @ Wqkv + bqkv -> q += , k += , v store
    gemm_kernel<2><<<dim3(768 / BN, MROWS / BM), blk, 0, stream>>>(
        x, Wqkv, bqkv, nullptr, MROWS, 256, 768, qb, kb, vb);
    // 3) attention
    attn_kernel<<<dim3(BATCH * NHEAD * (SEQ / 32)), blk, 0, stream>>>(
        qb, kb, vb, mask, ao);
    // 4) h = LN(x + ao)
    ln_kernel<<<dim3(MROWS), blk, 0, stream>>>(x, ao, ln1g, ln1b, hbuf);
    // 5) relu(h @ W1 + b1)
    gemm_kernel<1><<<dim3(1024 / BN, MROWS / BM), blk, 0, stream>>>(
        hbuf, W1, b1, tmp, MROWS, 256, 1024, nullptr, nullptr, nullptr);
    // 6) tmp @ W2 + b2
    gemm_kernel<0><<<dim3(256 / BN, MROWS / BM), blk, 0, stream>>>(
        tmp, W2, b2, f2, MROWS, 1024, 256, nullptr, nullptr, nullptr);
    // 7) out = LN(h + ffn)
    ln_kernel<<<dim3(MROWS), blk, 0, stream>>>(hbuf, f2, ln2g, ln2b, out);
}

// Round 2
// 627.102 us; speedup vs baseline: 2.2322x; 2.2322x over previous
//
#include <hip/hip_runtime.h>
#include <math.h>

// Problem constants (B=8, N=2048, D=256, H=8, Dh=32)
#define BATCH 8
#define SEQ   2048
#define DIM   256
#define NHEAD 8
#define DHEAD 32
#define MROWS (BATCH*SEQ)   // 16384

typedef short bf16x8 __attribute__((ext_vector_type(8)));
typedef float f32x4  __attribute__((ext_vector_type(4)));

// fp32 -> bf16 round-to-nearest-even (bits)
static __device__ __forceinline__ unsigned bf16rne(float f) {
    unsigned u = __float_as_uint(f);
    return (u + 0x7FFFu + ((u >> 16) & 1u)) >> 16;
}
// pack two fp32 -> bf16x2 word, `a` in low half (even key)
static __device__ __forceinline__ unsigned pack2(float a, float b) {
    return bf16rne(a) | (bf16rne(b) << 16);
}

// ---------------------------------------------------------------------------
// GEMM: C[M,Nc] = A[M,K] @ W[K,Nc] + bias, epilogue modes:
//   MODE 0: plain fp32 store     MODE 1: relu fp32 store
//   MODE 2: qkv: q,k = fp32 pos-partial + this, round bf16 -> u0/u1; v bf16 -> u2
//   MODE 3: pos: fp32 store to f0 (q_pos) / f1 (k_pos), [B,H,N,Dh] layout
// Tile: BM=128, BN=128, BK=16, 256 threads, 8x8 per thread.
// ---------------------------------------------------------------------------
#define BM 128
#define BN 128
#define BK 16

template<int MODE>
__global__ __launch_bounds__(256) void gemm_kernel(
    const float* __restrict__ A, const float* __restrict__ W,
    const float* __restrict__ bias, float* __restrict__ C,
    int M, int K, int Nc,
    const float* __restrict__ f0, const float* __restrict__ f1,
    float* __restrict__ g0, float* __restrict__ g1,
    unsigned short* __restrict__ u0, unsigned short* __restrict__ u1,
    unsigned short* __restrict__ u2)
{
    __shared__ float As[BK][BM + 4];
    __shared__ float Bs[BK][BN];

    const int t  = threadIdx.x;
    const int tx = t & 15;
    const int ty = t >> 4;
    const int r0 = blockIdx.y * BM;
    const int c0 = blockIdx.x * BN;

    float acc[8][8];
    #pragma unroll
    for (int i = 0; i < 8; ++i)
        #pragma unroll
        for (int j = 0; j < 8; ++j) acc[i][j] = 0.f;

    for (int k0 = 0; k0 < K; k0 += BK) {
        #pragma unroll
        for (int i = 0; i < 2; ++i) {
            int f  = t + i * 256;
            int m  = f >> 2;
            int kk = (f & 3) * 4;
            float4 av = *(const float4*)&A[(size_t)(r0 + m) * K + k0 + kk];
            As[kk + 0][m] = av.x; As[kk + 1][m] = av.y;
            As[kk + 2][m] = av.z; As[kk + 3][m] = av.w;
        }
        #pragma unroll
        for (int i = 0; i < 2; ++i) {
            int f  = t + i * 256;
            int kk = f >> 5;
            int n  = (f & 31) * 4;
            *(float4*)&Bs[kk][n] =
                *(const float4*)&W[(size_t)(k0 + kk) * Nc + c0 + n];
        }
        __syncthreads();

        #pragma unroll
        for (int kk = 0; kk < BK; ++kk) {
            float a[8], b[8];
            *(float4*)&a[0] = *(const float4*)&As[kk][ty * 4];
            *(float4*)&a[4] = *(const float4*)&As[kk][64 + ty * 4];
            *(float4*)&b[0] = *(const float4*)&Bs[kk][tx * 4];
            *(float4*)&b[4] = *(const float4*)&Bs[kk][64 + tx * 4];
            #pragma unroll
            for (int i = 0; i < 8; ++i)
                #pragma unroll
                for (int j = 0; j < 8; ++j)
                    acc[i][j] += a[i] * b[j];
        }
        __syncthreads();
    }

    #pragma unroll
    for (int ii = 0; ii < 8; ++ii) {
        int r = r0 + ((ii < 4) ? (ty * 4 + ii) : (64 + ty * 4 + ii - 4));
        #pragma unroll
        for (int ch = 0; ch < 2; ++ch) {
            int c = c0 + ch * 64 + tx * 4;
            float4 v;
            v.x = acc[ii][ch * 4 + 0] + bias[c + 0];
            v.y = acc[ii][ch * 4 + 1] + bias[c + 1];
            v.z = acc[ii][ch * 4 + 2] + bias[c + 2];
            v.w = acc[ii][ch * 4 + 3] + bias[c + 3];

            if (MODE == 0) {
                *(float4*)&C[(size_t)r * Nc + c] = v;
            } else if (MODE == 1) {
                v.x = fmaxf(v.x, 0.f); v.y = fmaxf(v.y, 0.f);
                v.z = fmaxf(v.z, 0.f); v.w = fmaxf(v.w, 0.f);
                *(float4*)&C[(size_t)r * Nc + c] = v;
            } else {
                int bb = r >> 11;
                int n  = r & (SEQ - 1);
                int which = c >> 8;        // 0:q 1:k 2:v
                int d  = c & 255;
                int hh = d >> 5;
                int dh = d & 31;
                size_t dst = (((size_t)bb * NHEAD + hh) * SEQ + n) * DHEAD + dh;
                if (MODE == 3) {
                    float* buf = (which == 0) ? g0 : g1;
                    *(float4*)&buf[dst] = v;
                } else {
                    if (which == 2) {
                        uint2 pk;
                        pk.x = pack2(v.x, v.y);
                        pk.y = pack2(v.z, v.w);
                        *(uint2*)&u2[dst] = pk;
                    } else {
                        const float* pbuf = which ? f1 : f0;
                        float4 old = *(const float4*)&pbuf[dst];
                        v.x += old.x; v.y += old.y; v.z += old.z; v.w += old.w;
                        unsigned short* ob = which ? u1 : u0;
                        uint2 pk;
                        pk.x = pack2(v.x, v.y);
                        pk.y = pack2(v.z, v.w);
                        *(uint2*)&ob[dst] = pk;
                    }
                }
            }
        }
    }
}

// ---------------------------------------------------------------------------
// V transpose: vb[b,h,n,d] bf16 -> vt[b,h,d,n] bf16.
// Coalesced reads (lanes span d), 16B writes along n.
// ---------------------------------------------------------------------------
__global__ __launch_bounds__(256) void vtrans_kernel(
    const unsigned short* __restrict__ vb, unsigned short* __restrict__ vt)
{
    int idx = blockIdx.x * 256 + threadIdx.x;   // 64 bh * 256 chunks * 32 d
    int d   = idx & 31;
    int c   = (idx >> 5) & 255;
    int bh  = idx >> 13;
    int n0  = c * 8;
    const unsigned short* src = vb + (size_t)bh * SEQ * 32 + d;
    union { unsigned short s[8]; uint4 v; } o;
    #pragma unroll
    for (int j = 0; j < 8; ++j) o.s[j] = src[(size_t)(n0 + j) * 32];
    *(uint4*)&vt[((size_t)bh * 32 + d) * SEQ + n0] = o.v;
}

// ---------------------------------------------------------------------------
// MFMA flash attention. Block = (b,h) x 128 q rows; 4 waves x 2 q-tiles(16).
// Swapped QK^T (S^T = K·Q^T) so softmax col = lane&15; PV as O^T = V^T·P^T so
// the rescale factor applies directly to the accumulator. Mask enters as the
// MFMA C-operand bias. No barriers in the K/V loop (K/V frags from L1).
// ---------------------------------------------------------------------------
__global__ __launch_bounds__(256) void attn_kernel(
    const unsigned short* __restrict__ Qb, const unsigned short* __restrict__ Kb,
    const unsigned short* __restrict__ Vt, const int* __restrict__ mask,
    float* __restrict__ O)
{
    __shared__ float bias_s[SEQ];        // 8 KB mask bias
    __shared__ float T[4][32][17];       // per-wave O^T transpose staging

    const int t    = threadIdx.x;
    const int wv   = t >> 6;
    const int lane = t & 63;
    const int g    = lane >> 4;
    const int lo   = lane & 15;

    const int bh   = blockIdx.x >> 4;
    const int qblk = blockIdx.x & 15;
    const int bb   = bh >> 3;
    const int hh   = bh & 7;
    const int qt   = qblk * 128 + wv * 32;

    const int* mrow = mask + bb * SEQ;
    for (int i = t; i < SEQ; i += 256)
        bias_s[i] = mrow[i] ? -3.0e38f : 0.0f;
    __syncthreads();

    const unsigned short* Qh = Qb + (size_t)bh * SEQ * 32;
    const unsigned short* Kh = Kb + (size_t)bh * SEQ * 32;
    const unsigned short* Vh = Vt + (size_t)bh * 32 * SEQ;

    bf16x8 qf[2];
    qf[0] = *(const bf16x8*)&Qh[(size_t)(qt + lo) * 32 + g * 8];
    qf[1] = *(const bf16x8*)&Qh[(size_t)(qt + 16 + lo) * 32 + g * 8];

    f32x4 acc[2][2];                     // [q-tile][d-half]
    #pragma unroll
    for (int i = 0; i < 2; ++i)
        #pragma unroll
        for (int hf = 0; hf < 2; ++hf)
            #pragma unroll
            for (int r = 0; r < 4; ++r) acc[i][hf][r] = 0.f;
    float m[2] = {-1e30f, -1e30f};
    float l[2] = {0.f, 0.f};

    const float CL = 0.25503485f;        // (1/sqrt(32)) * log2(e)

    for (int k0 = 0; k0 < SEQ; k0 += 32) {
        bf16x8 kfA = *(const bf16x8*)&Kh[(size_t)(k0 + lo) * 32 + g * 8];
        bf16x8 kfB = *(const bf16x8*)&Kh[(size_t)(k0 + 16 + lo) * 32 + g * 8];
        bf16x8 vf0 = *(const bf16x8*)&Vh[(size_t)lo * SEQ + k0 + g * 8];
        bf16x8 vf1 = *(const bf16x8*)&Vh[(size_t)(16 + lo) * SEQ + k0 + g * 8];

        f32x4 cb0, cb1;
        #pragma unroll
        for (int r = 0; r < 4; ++r) {
            cb0[r] = bias_s[k0 + 4 * g + r];
            cb1[r] = bias_s[k0 + 16 + 4 * g + r];
        }

        #pragma unroll
        for (int i = 0; i < 2; ++i) {
            // S^T block: rows = keys (16b+4g+r), col = q (lo)
            f32x4 s0 = __builtin_amdgcn_mfma_f32_16x16x32_bf16(kfA, qf[i], cb0, 0, 0, 0);
            f32x4 s1 = __builtin_amdgcn_mfma_f32_16x16x32_bf16(kfB, qf[i], cb1, 0, 0, 0);

            float tm = fmaxf(fmaxf(fmaxf(s0[0], s0[1]), fmaxf(s0[2], s0[3])),
                             fmaxf(fmaxf(s1[0], s1[1]), fmaxf(s1[2], s1[3])));
            tm = fmaxf(tm, __shfl_xor(tm, 16));
            tm = fmaxf(tm, __shfl_xor(tm, 32));
            float nm  = fmaxf(m[i], tm);
            float fac = exp2f((m[i] - nm) * CL);
            m[i] = nm;

            float p0[4], p1[4], tl = 0.f;
            #pragma unroll
            for (int r = 0; r < 4; ++r) {
                p0[r] = exp2f((s0[r] - nm) * CL);
                p1[r] = exp2f((s1[r] - nm) * CL);
                tl += p0[r] + p1[r];
            }
            tl += __shfl_xor(tl, 16);
            tl += __shfl_xor(tl, 32);
            l[i] = l[i] * fac + tl;
            #pragma unroll
            for (int hf = 0; hf < 2; ++hf)
                #pragma unroll
                for (int r = 0; r < 4; ++r) acc[i][hf][r] *= fac;

            // P^T -> PV B-frag: lane (g,lo) needs P[q=lo][keys 8g..8g+7]
            unsigned pk00 = pack2(p0[0], p0[1]);
            unsigned pk01 = pack2(p0[2], p0[3]);
            unsigned pk10 = pack2(p1[0], p1[1]);
            unsigned pk11 = pack2(p1[2], p1[3]);
            int s0l = ((g & 1) << 5) + lo;
            int s1l = s0l + 16;
            unsigned u00 = __shfl(pk00, s0l), u10 = __shfl(pk10, s0l);
            unsigned u01 = __shfl(pk01, s0l), u11 = __shfl(pk11, s0l);
            unsigned u02 = __shfl(pk00, s1l), u12 = __shfl(pk10, s1l);
            unsigned u03 = __shfl(pk01, s1l), u13 = __shfl(pk11, s1l);
            bool hi2 = g >= 2;
            union { unsigned u[4]; bf16x8 v; } pf;
            pf.u[0] = hi2 ? u10 : u00;
            pf.u[1] = hi2 ? u11 : u01;
            pf.u[2] = hi2 ? u12 : u02;
            pf.u[3] = hi2 ? u13 : u03;

            // O^T += V^T · P^T  (rows = d, col = q = lo)
            acc[i][0] = __builtin_amdgcn_mfma_f32_16x16x32_bf16(vf0, pf.v, acc[i][0], 0, 0, 0);
            acc[i][1] = __builtin_amdgcn_mfma_f32_16x16x32_bf16(vf1, pf.v, acc[i][1], 0, 0, 0);
        }
    }

    // epilogue: normalize, transpose O^T -> O via per-wave LDS tile, store
    #pragma unroll
    for (int i = 0; i < 2; ++i) {
        float inv = 1.0f / l[i];
        #pragma unroll
        for (int hf = 0; hf < 2; ++hf)
            #pragma unroll
            for (int r = 0; r < 4; ++r)
                T[wv][hf * 16 + g * 4 + r][lo] = acc[i][hf][r] * inv;
        __syncthreads();
        #pragma unroll
        for (int p = 0; p < 2; ++p) {
            int row = p * 8 + (lane >> 3);
            int d4  = (lane & 7) * 4;
            float4 ov;
            ov.x = T[wv][d4 + 0][row];
            ov.y = T[wv][d4 + 1][row];
            ov.z = T[wv][d4 + 2][row];
            ov.w = T[wv][d4 + 3][row];
            *(float4*)&O[(size_t)(bb * SEQ + qt + i * 16 + row) * DIM + hh * 32 + d4] = ov;
        }
        __syncthreads();
    }
}

// ---------------------------------------------------------------------------
// Fused residual + LayerNorm: one block = one 256-wide row.
// ---------------------------------------------------------------------------
__global__ __launch_bounds__(256) void ln_kernel(
    const float* __restrict__ X, const float* __restrict__ R,
    const float* __restrict__ gam, const float* __restrict__ bet,
    float* __restrict__ Y)
{
    const int row = blockIdx.x;
    const int t   = threadIdx.x;
    __shared__ float wsum[4];
    __shared__ float mu_s, rs_s;

    float v = X[(size_t)row * DIM + t] + R[(size_t)row * DIM + t];

    float s = v;
    #pragma unroll
    for (int off = 1; off < 64; off <<= 1) s += __shfl_xor(s, off);
    const int w = t >> 6, lane = t & 63;
    if (lane == 0) wsum[w] = s;
    __syncthreads();
    if (t == 0) mu_s = (wsum[0] + wsum[1] + wsum[2] + wsum[3]) * (1.f / 256.f);
    __syncthreads();
    const float mu = mu_s;
    const float d  = v - mu;

    float s2 = d * d;
    #pragma unroll
    for (int off = 1; off < 64; off <<= 1) s2 += __shfl_xor(s2, off);
    if (lane == 0) wsum[w] = s2;
    __syncthreads();
    if (t == 0)
        rs_s = rsqrtf((wsum[0] + wsum[1] + wsum[2] + wsum[3]) * (1.f / 256.f) + 1e-5f);
    __syncthreads();

    Y[(size_t)row * DIM + t] = d * rs_s * gam[t] + bet[t];
}

// ---------------------------------------------------------------------------
extern "C" void kernel_launch(void* const* d_in, const int* in_sizes, int n_in,
                              void* d_out, int out_size, void* d_ws, size_t ws_size,
                              hipStream_t stream)
{
    const float* x    = (const float*)d_in[0];
    const float* pos  = (const float*)d_in[1];
    const int*   mask = (const int*)d_in[2];
    const float* Wqkv = (const float*)d_in[3];
    const float* bqkv = (const float*)d_in[4];
    const float* Wpos = (const float*)d_in[5];
    const float* bpos = (const float*)d_in[6];
    const float* ln1g = (const float*)d_in[7];
    const float* ln1b = (const float*)d_in[8];
    const float* W1   = (const float*)d_in[9];
    const float* b1   = (const float*)d_in[10];
    const float* W2   = (const float*)d_in[11];
    const float* b2   = (const float*)d_in[12];
    const float* ln2g = (const float*)d_in[13];
    const float* ln2b = (const float*)d_in[14];
    float* out = (float*)d_out;

    // workspace (96 MB):
    //   [0,32M)   qp,kp fp32 pos-projections        \  region A (64 MB),
    //   [32M,64M) qb,kb,vb,vt bf16                  /  aliased later by FFN tmp
    //   [64M,80M) ao fp32 (later aliased by f2)
    //   [80M,96M) hbuf fp32
    float* base = (float*)d_ws;
    const size_t SZ = (size_t)MROWS * DIM;           // 4,194,304 elements
    float* qp = base;
    float* kp = base + SZ;
    unsigned short* qb = (unsigned short*)(base + 2 * SZ);
    unsigned short* kb = qb + SZ;
    unsigned short* vb = kb + SZ;
    unsigned short* vt = vb + SZ;
    float* tmp  = base;                              // FFN mid, aliases region A
    float* ao   = base + 4 * SZ;
    float* hbuf = base + 5 * SZ;
    float* f2   = base + 4 * SZ;                     // aliases ao (dead by then)

    dim3 blk(256);

    // 1) pos @ Wpos + bpos -> fp32 q_pos/k_pos scatter
    gemm_kernel<3><<<dim3(512 / BN, MROWS / BM), blk, 0, stream>>>(
        pos, Wpos, bpos, nullptr, MROWS, 512, 512,
        nullptr, nullptr, qp, kp, nullptr, nullptr, nullptr);
    // 2) x @ Wqkv + bqkv -> q,k (+pos, ->bf16), v (->bf16)
    gemm_kernel<2><<<dim3(768 / BN, MROWS / BM), blk, 0, stream>>>(
        x, Wqkv, bqkv, nullptr, MROWS, 256, 768,
        qp, kp, nullptr, nullptr, qb, kb, vb);
    // 3) V transpose -> vt[b,h,d,n]
    vtrans_kernel<<<dim3(2048), blk, 0, stream>>>(vb, vt);
    // 4) MFMA attention
    attn_kernel<<<dim3(BATCH * NHEAD * (SEQ / 128)), blk, 0, stream>>>(
        qb, kb, vt, mask, ao);
    // 5) h = LN(x + ao)
    ln_kernel<<<dim3(MROWS), blk, 0, stream>>>(x, ao, ln1g, ln1b, hbuf);
    // 6) relu(h @ W1 + b1)
    gemm_kernel<1><<<dim3(1024 / BN, MROWS / BM), blk, 0, stream>>>(
        hbuf, W1, b1, tmp, MROWS, 256, 1024,
        nullptr, nullptr, nullptr, nullptr, nullptr, nullptr, nullptr);
    // 7) tmp @ W2 + b2
    gemm_kernel<0><<<dim3(256 / BN, MROWS / BM), blk, 0, stream>>>(
        tmp, W2, b2, f2, MROWS, 1024, 256,
        nullptr, nullptr, nullptr, nullptr, nullptr, nullptr, nullptr);
    // 8) out = LN(h + ffn)
    ln_kernel<<<dim3(MROWS), blk, 0, stream>>>(hbuf, f2, ln2g, ln2b, out);
}

// Round 3
// 382.785 us; speedup vs baseline: 3.6568x; 1.6383x over previous
//
#include <hip/hip_runtime.h>
#include <math.h>

// Problem constants (B=8, N=2048, D=256, H=8, Dh=32)
#define BATCH 8
#define SEQ   2048
#define DIM   256
#define NHEAD 8
#define DHEAD 32
#define MROWS (BATCH*SEQ)   // 16384

typedef short bf16x8 __attribute__((ext_vector_type(8)));
typedef float f32x4  __attribute__((ext_vector_type(4)));

// fp32 -> bf16 round-to-nearest-even (bits)
static __device__ __forceinline__ unsigned bf16rne(float f) {
    unsigned u = __float_as_uint(f);
    return (u + 0x7FFFu + ((u >> 16) & 1u)) >> 16;
}
static __device__ __forceinline__ unsigned pack2(float a, float b) {
    return bf16rne(a) | (bf16rne(b) << 16);
}

// ---------------------------------------------------------------------------
// fp32 -> bf16 convert, 8 elements/thread
// ---------------------------------------------------------------------------
__global__ __launch_bounds__(256) void conv_kernel(
    const float* __restrict__ src, unsigned short* __restrict__ dst, int n8)
{
    int i = blockIdx.x * 256 + threadIdx.x;
    if (i >= n8) return;
    float4 a = ((const float4*)src)[2 * i];
    float4 b = ((const float4*)src)[2 * i + 1];
    union { unsigned short s[8]; uint4 v; } o;
    o.s[0] = bf16rne(a.x); o.s[1] = bf16rne(a.y);
    o.s[2] = bf16rne(a.z); o.s[3] = bf16rne(a.w);
    o.s[4] = bf16rne(b.x); o.s[5] = bf16rne(b.y);
    o.s[6] = bf16rne(b.z); o.s[7] = bf16rne(b.w);
    ((uint4*)dst)[i] = o.v;
}

// ---------------------------------------------------------------------------
// Weight transpose+convert: W[K,N] fp32 -> Wt[N,K] bf16. 32x32 LDS tiles.
// grid = (N/32, K/32), block 256 (32 wide x 8).
// ---------------------------------------------------------------------------
__global__ __launch_bounds__(256) void wtrans_kernel(
    const float* __restrict__ W, unsigned short* __restrict__ Wt, int K, int N)
{
    __shared__ float tile[32][33];
    const int tn0 = blockIdx.x * 32;
    const int tk0 = blockIdx.y * 32;
    const int tx = threadIdx.x & 31;
    const int ty = threadIdx.x >> 5;
    #pragma unroll
    for (int r = ty; r < 32; r += 8)
        tile[r][tx] = W[(size_t)(tk0 + r) * N + tn0 + tx];
    __syncthreads();
    #pragma unroll
    for (int r = ty; r < 32; r += 8)
        Wt[(size_t)(tn0 + r) * K + tk0 + tx] = (unsigned short)bf16rne(tile[tx][r]);
}

// ---------------------------------------------------------------------------
// bf16 MFMA GEMM: C[M,Nc] = A[M,K] (bf16) @ Wt[Nc,K]^T (bf16) + bias.
// Block 128x128, 4 waves 2x2, each wave 4x4 frags of 16x16x32. Operands
// straight from global (L2-resident at these sizes) -> no LDS, no barriers.
// Epilogue modes:
//   0: fp32 store to C            1: relu -> bf16 store to Cb
//   2: qkv scatter (q,k: + fp32 qp/kp partial -> bf16 u0/u1; v -> bf16 u2)
//   3: pos scatter (fp32 -> g0/g1), [B,H,N,Dh] layout
// ---------------------------------------------------------------------------
template<int MODE>
__global__ __launch_bounds__(256) void mgemm_kernel(
    const unsigned short* __restrict__ A, const unsigned short* __restrict__ Wt,
    const float* __restrict__ bias, float* __restrict__ C,
    unsigned short* __restrict__ Cb, int M, int K, int Nc,
    const float* __restrict__ qp, const float* __restrict__ kp,
    float* __restrict__ g0, float* __restrict__ g1,
    unsigned short* __restrict__ u0, unsigned short* __restrict__ u1,
    unsigned short* __restrict__ u2)
{
    const int t    = threadIdx.x;
    const int wv   = t >> 6;
    const int lane = t & 63;
    const int g    = lane >> 4;
    const int lo   = lane & 15;
    const int wr   = wv >> 1;
    const int wc   = wv & 1;
    const int r0   = blockIdx.y * 128 + wr * 64;
    const int c0   = blockIdx.x * 128 + wc * 64;

    f32x4 acc[4][4];
    #pragma unroll
    for (int i = 0; i < 4; ++i)
        #pragma unroll
        for (int j = 0; j < 4; ++j)
            #pragma unroll
            for (int r = 0; r < 4; ++r) acc[i][j][r] = 0.f;

    const unsigned short* aP[4];
    const unsigned short* bP[4];
    #pragma unroll
    for (int i = 0; i < 4; ++i) {
        aP[i] = A  + (size_t)(r0 + 16 * i + lo) * K + g * 8;
        bP[i] = Wt + (size_t)(c0 + 16 * i + lo) * K + g * 8;
    }

    for (int k0 = 0; k0 < K; k0 += 32) {
        bf16x8 af[4], bf[4];
        #pragma unroll
        for (int i = 0; i < 4; ++i) af[i] = *(const bf16x8*)(aP[i] + k0);
        #pragma unroll
        for (int j = 0; j < 4; ++j) bf[j] = *(const bf16x8*)(bP[j] + k0);
        #pragma unroll
        for (int i = 0; i < 4; ++i)
            #pragma unroll
            for (int j = 0; j < 4; ++j)
                acc[i][j] = __builtin_amdgcn_mfma_f32_16x16x32_bf16(
                    af[i], bf[j], acc[i][j], 0, 0, 0);
    }

    // epilogue: frag (i,j), reg r -> row = r0+16i+g*4+r, col = c0+16j+lo
    #pragma unroll
    for (int j = 0; j < 4; ++j) {
        const int col = c0 + 16 * j + lo;
        const float bs = bias[col];
        #pragma unroll
        for (int i = 0; i < 4; ++i) {
            #pragma unroll
            for (int r = 0; r < 4; ++r) {
                const int row = r0 + 16 * i + g * 4 + r;
                float v = acc[i][j][r] + bs;
                if (MODE == 0) {
                    C[(size_t)row * Nc + col] = v;
                } else if (MODE == 1) {
                    Cb[(size_t)row * Nc + col] =
                        (unsigned short)bf16rne(fmaxf(v, 0.f));
                } else {
                    const int bb = row >> 11;
                    const int nn = row & (SEQ - 1);
                    const int which = col >> 8;
                    const int d  = col & 255;
                    const int hh = d >> 5;
                    const int dh = d & 31;
                    const size_t dst =
                        (((size_t)bb * NHEAD + hh) * SEQ + nn) * DHEAD + dh;
                    if (MODE == 3) {
                        (which ? g1 : g0)[dst] = v;
                    } else {
                        if (which == 2) {
                            u2[dst] = (unsigned short)bf16rne(v);
                        } else {
                            v += (which ? kp : qp)[dst];
                            (which ? u1 : u0)[dst] = (unsigned short)bf16rne(v);
                        }
                    }
                }
            }
        }
    }
}

// ---------------------------------------------------------------------------
// V transpose: vb[b,h,n,d] bf16 -> vt[b,h,d,n] bf16.
// ---------------------------------------------------------------------------
__global__ __launch_bounds__(256) void vtrans_kernel(
    const unsigned short* __restrict__ vb, unsigned short* __restrict__ vt)
{
    int idx = blockIdx.x * 256 + threadIdx.x;
    int d   = idx & 31;
    int c   = (idx >> 5) & 255;
    int bh  = idx >> 13;
    int n0  = c * 8;
    const unsigned short* src = vb + (size_t)bh * SEQ * 32 + d;
    union { unsigned short s[8]; uint4 v; } o;
    #pragma unroll
    for (int j = 0; j < 8; ++j) o.s[j] = src[(size_t)(n0 + j) * 32];
    *(uint4*)&vt[((size_t)bh * 32 + d) * SEQ + n0] = o.v;
}

// ---------------------------------------------------------------------------
// MFMA flash attention (unchanged from round 2).
// ---------------------------------------------------------------------------
__global__ __launch_bounds__(256) void attn_kernel(
    const unsigned short* __restrict__ Qb, const unsigned short* __restrict__ Kb,
    const unsigned short* __restrict__ Vt, const int* __restrict__ mask,
    float* __restrict__ O)
{
    __shared__ float bias_s[SEQ];
    __shared__ float T[4][32][17];

    const int t    = threadIdx.x;
    const int wv   = t >> 6;
    const int lane = t & 63;
    const int g    = lane >> 4;
    const int lo   = lane & 15;

    const int bh   = blockIdx.x >> 4;
    const int qblk = blockIdx.x & 15;
    const int bb   = bh >> 3;
    const int hh   = bh & 7;
    const int qt   = qblk * 128 + wv * 32;

    const int* mrow = mask + bb * SEQ;
    for (int i = t; i < SEQ; i += 256)
        bias_s[i] = mrow[i] ? -3.0e38f : 0.0f;
    __syncthreads();

    const unsigned short* Qh = Qb + (size_t)bh * SEQ * 32;
    const unsigned short* Kh = Kb + (size_t)bh * SEQ * 32;
    const unsigned short* Vh = Vt + (size_t)bh * 32 * SEQ;

    bf16x8 qf[2];
    qf[0] = *(const bf16x8*)&Qh[(size_t)(qt + lo) * 32 + g * 8];
    qf[1] = *(const bf16x8*)&Qh[(size_t)(qt + 16 + lo) * 32 + g * 8];

    f32x4 acc[2][2];
    #pragma unroll
    for (int i = 0; i < 2; ++i)
        #pragma unroll
        for (int hf = 0; hf < 2; ++hf)
            #pragma unroll
            for (int r = 0; r < 4; ++r) acc[i][hf][r] = 0.f;
    float m[2] = {-1e30f, -1e30f};
    float l[2] = {0.f, 0.f};

    const float CL = 0.25503485f;        // (1/sqrt(32)) * log2(e)

    for (int k0 = 0; k0 < SEQ; k0 += 32) {
        bf16x8 kfA = *(const bf16x8*)&Kh[(size_t)(k0 + lo) * 32 + g * 8];
        bf16x8 kfB = *(const bf16x8*)&Kh[(size_t)(k0 + 16 + lo) * 32 + g * 8];
        bf16x8 vf0 = *(const bf16x8*)&Vh[(size_t)lo * SEQ + k0 + g * 8];
        bf16x8 vf1 = *(const bf16x8*)&Vh[(size_t)(16 + lo) * SEQ + k0 + g * 8];

        f32x4 cb0, cb1;
        #pragma unroll
        for (int r = 0; r < 4; ++r) {
            cb0[r] = bias_s[k0 + 4 * g + r];
            cb1[r] = bias_s[k0 + 16 + 4 * g + r];
        }

        #pragma unroll
        for (int i = 0; i < 2; ++i) {
            f32x4 s0 = __builtin_amdgcn_mfma_f32_16x16x32_bf16(kfA, qf[i], cb0, 0, 0, 0);
            f32x4 s1 = __builtin_amdgcn_mfma_f32_16x16x32_bf16(kfB, qf[i], cb1, 0, 0, 0);

            float tm = fmaxf(fmaxf(fmaxf(s0[0], s0[1]), fmaxf(s0[2], s0[3])),
                             fmaxf(fmaxf(s1[0], s1[1]), fmaxf(s1[2], s1[3])));
            tm = fmaxf(tm, __shfl_xor(tm, 16));
            tm = fmaxf(tm, __shfl_xor(tm, 32));
            float nm  = fmaxf(m[i], tm);
            float fac = exp2f((m[i] - nm) * CL);
            m[i] = nm;

            float p0[4], p1[4], tl = 0.f;
            #pragma unroll
            for (int r = 0; r < 4; ++r) {
                p0[r] = exp2f((s0[r] - nm) * CL);
                p1[r] = exp2f((s1[r] - nm) * CL);
                tl += p0[r] + p1[r];
            }
            tl += __shfl_xor(tl, 16);
            tl += __shfl_xor(tl, 32);
            l[i] = l[i] * fac + tl;
            #pragma unroll
            for (int hf = 0; hf < 2; ++hf)
                #pragma unroll
                for (int r = 0; r < 4; ++r) acc[i][hf][r] *= fac;

            unsigned pk00 = pack2(p0[0], p0[1]);
            unsigned pk01 = pack2(p0[2], p0[3]);
            unsigned pk10 = pack2(p1[0], p1[1]);
            unsigned pk11 = pack2(p1[2], p1[3]);
            int s0l = ((g & 1) << 5) + lo;
            int s1l = s0l + 16;
            unsigned u00 = __shfl(pk00, s0l), u10 = __shfl(pk10, s0l);
            unsigned u01 = __shfl(pk01, s0l), u11 = __shfl(pk11, s0l);
            unsigned u02 = __shfl(pk00, s1l), u12 = __shfl(pk10, s1l);
            unsigned u03 = __shfl(pk01, s1l), u13 = __shfl(pk11, s1l);
            bool hi2 = g >= 2;
            union { unsigned u[4]; bf16x8 v; } pf;
            pf.u[0] = hi2 ? u10 : u00;
            pf.u[1] = hi2 ? u11 : u01;
            pf.u[2] = hi2 ? u12 : u02;
            pf.u[3] = hi2 ? u13 : u03;

            acc[i][0] = __builtin_amdgcn_mfma_f32_16x16x32_bf16(vf0, pf.v, acc[i][0], 0, 0, 0);
            acc[i][1] = __builtin_amdgcn_mfma_f32_16x16x32_bf16(vf1, pf.v, acc[i][1], 0, 0, 0);
        }
    }

    #pragma unroll
    for (int i = 0; i < 2; ++i) {
        float inv = 1.0f / l[i];
        #pragma unroll
        for (int hf = 0; hf < 2; ++hf)
            #pragma unroll
            for (int r = 0; r < 4; ++r)
                T[wv][hf * 16 + g * 4 + r][lo] = acc[i][hf][r] * inv;
        __syncthreads();
        #pragma unroll
        for (int p = 0; p < 2; ++p) {
            int row = p * 8 + (lane >> 3);
            int d4  = (lane & 7) * 4;
            float4 ov;
            ov.x = T[wv][d4 + 0][row];
            ov.y = T[wv][d4 + 1][row];
            ov.z = T[wv][d4 + 2][row];
            ov.w = T[wv][d4 + 3][row];
            *(float4*)&O[(size_t)(bb * SEQ + qt + i * 16 + row) * DIM + hh * 32 + d4] = ov;
        }
        __syncthreads();
    }
}

// ---------------------------------------------------------------------------
// Fused residual + LayerNorm, optional bf16 secondary output.
// ---------------------------------------------------------------------------
__global__ __launch_bounds__(256) void ln_kernel(
    const float* __restrict__ X, const float* __restrict__ R,
    const float* __restrict__ gam, const float* __restrict__ bet,
    float* __restrict__ Y, unsigned short* __restrict__ Yb)
{
    const int row = blockIdx.x;
    const int t   = threadIdx.x;
    __shared__ float wsum[4];
    __shared__ float mu_s, rs_s;

    float v = X[(size_t)row * DIM + t] + R[(size_t)row * DIM + t];

    float s = v;
    #pragma unroll
    for (int off = 1; off < 64; off <<= 1) s += __shfl_xor(s, off);
    const int w = t >> 6, lane = t & 63;
    if (lane == 0) wsum[w] = s;
    __syncthreads();
    if (t == 0) mu_s = (wsum[0] + wsum[1] + wsum[2] + wsum[3]) * (1.f / 256.f);
    __syncthreads();
    const float mu = mu_s;
    const float d  = v - mu;

    float s2 = d * d;
    #pragma unroll
    for (int off = 1; off < 64; off <<= 1) s2 += __shfl_xor(s2, off);
    if (lane == 0) wsum[w] = s2;
    __syncthreads();
    if (t == 0)
        rs_s = rsqrtf((wsum[0] + wsum[1] + wsum[2] + wsum[3]) * (1.f / 256.f) + 1e-5f);
    __syncthreads();

    float y = d * rs_s * gam[t] + bet[t];
    Y[(size_t)row * DIM + t] = y;
    if (Yb) Yb[(size_t)row * DIM + t] = (unsigned short)bf16rne(y);
}

// ---------------------------------------------------------------------------
extern "C" void kernel_launch(void* const* d_in, const int* in_sizes, int n_in,
                              void* d_out, int out_size, void* d_ws, size_t ws_size,
                              hipStream_t stream)
{
    const float* x    = (const float*)d_in[0];
    const float* pos  = (const float*)d_in[1];
    const int*   mask = (const int*)d_in[2];
    const float* Wqkv = (const float*)d_in[3];
    const float* bqkv = (const float*)d_in[4];
    const float* Wpos = (const float*)d_in[5];
    const float* bpos = (const float*)d_in[6];
    const float* ln1g = (const float*)d_in[7];
    const float* ln1b = (const float*)d_in[8];
    const float* W1   = (const float*)d_in[9];
    const float* b1   = (const float*)d_in[10];
    const float* W2   = (const float*)d_in[11];
    const float* b2   = (const float*)d_in[12];
    const float* ln2g = (const float*)d_in[13];
    const float* ln2b = (const float*)d_in[14];
    float* out = (float*)d_out;

    // Workspace layout (90 MB), regions reused by lifetime:
    //  [ 0,16M)  qp   (s3-4)   | ao (s6-7)  | mid lo (s8-9)
    //  [16,32M)  kp   (s3-4)   |            | mid hi (s8-9)
    //  [32,40M)  xb   (s1-4)   | hb (s7-8)
    //  [40,56M)  posb (s1-3)   | hbuf (s7-10)
    //  [56,64M)  qb   (s4-6)
    //  [64,72M)  kb   (s4-6)
    //  [72,80M)  vb   (s4-5)
    //  [80,88M)  vt   (s5-6)
    //  [88,90M)  Wt   (s2-9)
    //  f2 lives in d_out (written s9, LN2 in-place s10).
    char* base = (char*)d_ws;
    const size_t MB = 1024 * 1024;
    const size_t SZ = (size_t)MROWS * DIM;           // 4,194,304 elements
    float*          qp   = (float*)(base + 0);
    float*          kp   = (float*)(base + 16 * MB);
    float*          ao   = (float*)(base + 0);
    unsigned short* mid  = (unsigned short*)(base + 0);
    unsigned short* xb   = (unsigned short*)(base + 32 * MB);
    unsigned short* hb   = (unsigned short*)(base + 32 * MB);
    unsigned short* posb = (unsigned short*)(base + 40 * MB);
    float*          hbuf = (float*)(base + 40 * MB);
    unsigned short* qb   = (unsigned short*)(base + 56 * MB);
    unsigned short* kb   = (unsigned short*)(base + 64 * MB);
    unsigned short* vb   = (unsigned short*)(base + 72 * MB);
    unsigned short* vt   = (unsigned short*)(base + 80 * MB);
    unsigned short* wq   = (unsigned short*)(base + 88 * MB);   // [768,256]
    unsigned short* wp   = wq + 768 * 256;                      // [512,512]
    unsigned short* w1   = wp + 512 * 512;                      // [1024,256]
    unsigned short* w2   = w1 + 1024 * 256;                     // [256,1024]
    float*          f2   = out;

    dim3 blk(256);

    // s1) activation converts
    conv_kernel<<<dim3((SZ / 8) / 256), blk, 0, stream>>>(x, xb, SZ / 8);
    conv_kernel<<<dim3((2 * SZ / 8) / 256), blk, 0, stream>>>(pos, posb, 2 * SZ / 8);
    // s2) weight transpose+convert
    wtrans_kernel<<<dim3(768 / 32, 256 / 32), blk, 0, stream>>>(Wqkv, wq, 256, 768);
    wtrans_kernel<<<dim3(512 / 32, 512 / 32), blk, 0, stream>>>(Wpos, wp, 512, 512);
    wtrans_kernel<<<dim3(1024 / 32, 256 / 32), blk, 0, stream>>>(W1, w1, 256, 1024);
    wtrans_kernel<<<dim3(256 / 32, 1024 / 32), blk, 0, stream>>>(W2, w2, 1024, 256);
    // s3) pos @ Wpos + bpos -> fp32 qp/kp scatter
    mgemm_kernel<3><<<dim3(512 / 128, MROWS / 128), blk, 0, stream>>>(
        posb, wp, bpos, nullptr, nullptr, MROWS, 512, 512,
        nullptr, nullptr, qp, kp, nullptr, nullptr, nullptr);
    // s4) x @ Wqkv + bqkv -> q,k (+pos -> bf16), v (bf16)
    mgemm_kernel<2><<<dim3(768 / 128, MROWS / 128), blk, 0, stream>>>(
        xb, wq, bqkv, nullptr, nullptr, MROWS, 256, 768,
        qp, kp, nullptr, nullptr, qb, kb, vb);
    // s5) V transpose
    vtrans_kernel<<<dim3(2048), blk, 0, stream>>>(vb, vt);
    // s6) attention -> ao
    attn_kernel<<<dim3(BATCH * NHEAD * (SEQ / 128)), blk, 0, stream>>>(
        qb, kb, vt, mask, ao);
    // s7) h = LN(x + ao) -> hbuf fp32 + hb bf16
    ln_kernel<<<dim3(MROWS), blk, 0, stream>>>(x, ao, ln1g, ln1b, hbuf, hb);
    // s8) relu(h @ W1 + b1) -> mid bf16
    mgemm_kernel<1><<<dim3(1024 / 128, MROWS / 128), blk, 0, stream>>>(
        hb, w1, b1, nullptr, mid, MROWS, 256, 1024,
        nullptr, nullptr, nullptr, nullptr, nullptr, nullptr, nullptr);
    // s9) mid @ W2 + b2 -> f2 (= d_out)
    mgemm_kernel<0><<<dim3(256 / 128, MROWS / 128), blk, 0, stream>>>(
        mid, w2, b2, f2, nullptr, MROWS, 1024, 256,
        nullptr, nullptr, nullptr, nullptr, nullptr, nullptr, nullptr);
    // s10) out = LN(h + ffn), in-place on d_out
    ln_kernel<<<dim3(MROWS), blk, 0, stream>>>(hbuf, f2, ln2g, ln2b, out, nullptr);
}

// Round 4
// 345.318 us; speedup vs baseline: 4.0536x; 1.1085x over previous
//
#include <hip/hip_runtime.h>
#include <math.h>

// Problem constants (B=8, N=2048, D=256, H=8, Dh=32)
#define BATCH 8
#define SEQ   2048
#define DIM   256
#define NHEAD 8
#define DHEAD 32
#define MROWS (BATCH*SEQ)   // 16384

typedef short bf16x8 __attribute__((ext_vector_type(8)));
typedef float f32x4  __attribute__((ext_vector_type(4)));

#define CLSCALE 0.25503485f   // log2(e)/sqrt(32): Q pre-scaled by this in mgemm

// fp32 -> bf16 round-to-nearest-even (bits)
static __device__ __forceinline__ unsigned bf16rne(float f) {
    unsigned u = __float_as_uint(f);
    return (u + 0x7FFFu + ((u >> 16) & 1u)) >> 16;
}

// ---------------------------------------------------------------------------
// fp32 -> bf16 convert, 8 elements/thread
// ---------------------------------------------------------------------------
__global__ __launch_bounds__(256) void conv_kernel(
    const float* __restrict__ src, unsigned short* __restrict__ dst, int n8)
{
    int i = blockIdx.x * 256 + threadIdx.x;
    if (i >= n8) return;
    float4 a = ((const float4*)src)[2 * i];
    float4 b = ((const float4*)src)[2 * i + 1];
    union { unsigned short s[8]; uint4 v; } o;
    o.s[0] = bf16rne(a.x); o.s[1] = bf16rne(a.y);
    o.s[2] = bf16rne(a.z); o.s[3] = bf16rne(a.w);
    o.s[4] = bf16rne(b.x); o.s[5] = bf16rne(b.y);
    o.s[6] = bf16rne(b.z); o.s[7] = bf16rne(b.w);
    ((uint4*)dst)[i] = o.v;
}

// ---------------------------------------------------------------------------
// Weight transpose+convert: W[K,N] fp32 -> Wt[N,K] bf16. 32x32 LDS tiles.
// ---------------------------------------------------------------------------
__global__ __launch_bounds__(256) void wtrans_kernel(
    const float* __restrict__ W, unsigned short* __restrict__ Wt, int K, int N)
{
    __shared__ float tile[32][33];
    const int tn0 = blockIdx.x * 32;
    const int tk0 = blockIdx.y * 32;
    const int tx = threadIdx.x & 31;
    const int ty = threadIdx.x >> 5;
    #pragma unroll
    for (int r = ty; r < 32; r += 8)
        tile[r][tx] = W[(size_t)(tk0 + r) * N + tn0 + tx];
    __syncthreads();
    #pragma unroll
    for (int r = ty; r < 32; r += 8)
        Wt[(size_t)(tn0 + r) * K + tk0 + tx] = (unsigned short)bf16rne(tile[tx][r]);
}

// ---------------------------------------------------------------------------
// bf16 MFMA GEMM: C[M,Nc] = A[M,K] (bf16) @ Wt[Nc,K]^T (bf16) + bias.
// Block 128x128, 4 waves 2x2, each wave 4x4 frags of 16x16x32, operands
// direct from global. Epilogue modes:
//   0: fp32 store   1: relu->bf16 store
//   2: qkv scatter (q: (+qp)*CLSCALE ->bf16, k: (+kp)->bf16, v->bf16)
//   3: pos scatter (fp32 -> g0/g1), [B,H,N,Dh] layout
// ---------------------------------------------------------------------------
template<int MODE>
__global__ __launch_bounds__(256) void mgemm_kernel(
    const unsigned short* __restrict__ A, const unsigned short* __restrict__ Wt,
    const float* __restrict__ bias, float* __restrict__ C,
    unsigned short* __restrict__ Cb, int M, int K, int Nc,
    const float* __restrict__ qp, const float* __restrict__ kp,
    float* __restrict__ g0, float* __restrict__ g1,
    unsigned short* __restrict__ u0, unsigned short* __restrict__ u1,
    unsigned short* __restrict__ u2)
{
    const int t    = threadIdx.x;
    const int wv   = t >> 6;
    const int lane = t & 63;
    const int g    = lane >> 4;
    const int lo   = lane & 15;
    const int wr   = wv >> 1;
    const int wc   = wv & 1;
    const int r0   = blockIdx.y * 128 + wr * 64;
    const int c0   = blockIdx.x * 128 + wc * 64;

    f32x4 acc[4][4];
    #pragma unroll
    for (int i = 0; i < 4; ++i)
        #pragma unroll
        for (int j = 0; j < 4; ++j)
            #pragma unroll
            for (int r = 0; r < 4; ++r) acc[i][j][r] = 0.f;

    const unsigned short* aP[4];
    const unsigned short* bP[4];
    #pragma unroll
    for (int i = 0; i < 4; ++i) {
        aP[i] = A  + (size_t)(r0 + 16 * i + lo) * K + g * 8;
        bP[i] = Wt + (size_t)(c0 + 16 * i + lo) * K + g * 8;
    }

    for (int k0 = 0; k0 < K; k0 += 32) {
        bf16x8 af[4], bf[4];
        #pragma unroll
        for (int i = 0; i < 4; ++i) af[i] = *(const bf16x8*)(aP[i] + k0);
        #pragma unroll
        for (int j = 0; j < 4; ++j) bf[j] = *(const bf16x8*)(bP[j] + k0);
        #pragma unroll
        for (int i = 0; i < 4; ++i)
            #pragma unroll
            for (int j = 0; j < 4; ++j)
                acc[i][j] = __builtin_amdgcn_mfma_f32_16x16x32_bf16(
                    af[i], bf[j], acc[i][j], 0, 0, 0);
    }

    #pragma unroll
    for (int j = 0; j < 4; ++j) {
        const int col = c0 + 16 * j + lo;
        const float bs = bias[col];
        #pragma unroll
        for (int i = 0; i < 4; ++i) {
            #pragma unroll
            for (int r = 0; r < 4; ++r) {
                const int row = r0 + 16 * i + g * 4 + r;
                float v = acc[i][j][r] + bs;
                if (MODE == 0) {
                    C[(size_t)row * Nc + col] = v;
                } else if (MODE == 1) {
                    Cb[(size_t)row * Nc + col] =
                        (unsigned short)bf16rne(fmaxf(v, 0.f));
                } else {
                    const int bb = row >> 11;
                    const int nn = row & (SEQ - 1);
                    const int which = col >> 8;
                    const int d  = col & 255;
                    const int hh = d >> 5;
                    const int dh = d & 31;
                    const size_t dst =
                        (((size_t)bb * NHEAD + hh) * SEQ + nn) * DHEAD + dh;
                    if (MODE == 3) {
                        (which ? g1 : g0)[dst] = v;
                    } else {
                        if (which == 2) {
                            u2[dst] = (unsigned short)bf16rne(v);
                        } else if (which == 1) {
                            v += kp[dst];
                            u1[dst] = (unsigned short)bf16rne(v);
                        } else {
                            v = (v + qp[dst]) * CLSCALE;   // fold softmax scale
                            u0[dst] = (unsigned short)bf16rne(v);
                        }
                    }
                }
            }
        }
    }
}

// ---------------------------------------------------------------------------
// V transpose: vb[b,h,n,d] bf16 -> vt[b,h,d,n] bf16.
// ---------------------------------------------------------------------------
__global__ __launch_bounds__(256) void vtrans_kernel(
    const unsigned short* __restrict__ vb, unsigned short* __restrict__ vt)
{
    int idx = blockIdx.x * 256 + threadIdx.x;
    int d   = idx & 31;
    int c   = (idx >> 5) & 255;
    int bh  = idx >> 13;
    int n0  = c * 8;
    const unsigned short* src = vb + (size_t)bh * SEQ * 32 + d;
    union { unsigned short s[8]; uint4 v; } o;
    #pragma unroll
    for (int j = 0; j < 8; ++j) o.s[j] = src[(size_t)(n0 + j) * 32];
    *(uint4*)&vt[((size_t)bh * 32 + d) * SEQ + n0] = o.v;
}

// ---------------------------------------------------------------------------
// MFMA flash attention, 64-key batched softmax.
// Block = (b,h) x 128 q rows; 4 waves x 2 q-tiles(16). Swapped QK^T
// (S^T = K·Q^T, col = q = lane&15). Q pre-scaled by log2e/sqrt(Dh) upstream;
// mask enters as MFMA C-operand bias (log2-units). Defer-max (THR=0, exact).
// P -> bf16 via v_cvt_pk_bf16_f32; redistribution via 16 ds_bpermute / 64 keys.
// ---------------------------------------------------------------------------
__global__ __launch_bounds__(256, 3) void attn_kernel(
    const unsigned short* __restrict__ Qb, const unsigned short* __restrict__ Kb,
    const unsigned short* __restrict__ Vt, const int* __restrict__ mask,
    float* __restrict__ O)
{
    __shared__ float bias_s[SEQ];        // 8 KB mask bias (log2-units: 0 / -3e38)
    __shared__ float T[4][32][17];       // per-wave O^T transpose staging

    const int t    = threadIdx.x;
    const int wv   = t >> 6;
    const int lane = t & 63;
    const int g    = lane >> 4;
    const int lo   = lane & 15;

    const int bh   = blockIdx.x >> 4;
    const int qblk = blockIdx.x & 15;
    const int bb   = bh >> 3;
    const int hh   = bh & 7;
    const int qt   = qblk * 128 + wv * 32;

    const int* mrow = mask + bb * SEQ;
    for (int i = t; i < SEQ; i += 256)
        bias_s[i] = mrow[i] ? -3.0e38f : 0.0f;
    __syncthreads();

    const unsigned short* Qh = Qb + (size_t)bh * SEQ * 32;
    const unsigned short* Kh = Kb + (size_t)bh * SEQ * 32;
    const unsigned short* Vh = Vt + (size_t)bh * 32 * SEQ;

    bf16x8 qf[2];
    qf[0] = *(const bf16x8*)&Qh[(size_t)(qt + lo) * 32 + g * 8];
    qf[1] = *(const bf16x8*)&Qh[(size_t)(qt + 16 + lo) * 32 + g * 8];

    f32x4 acc[2][2];                     // [q-tile][d-half]
    #pragma unroll
    for (int i = 0; i < 2; ++i)
        #pragma unroll
        for (int hf = 0; hf < 2; ++hf)
            #pragma unroll
            for (int r = 0; r < 4; ++r) acc[i][hf][r] = 0.f;
    float m[2] = {-1e30f, -1e30f};
    float l[2] = {0.f, 0.f};

    // bpermute byte addresses (hoisted): source lanes 32*(g&1)+lo and +16
    const int a0 = ((((g & 1) << 5) + lo) << 2);
    const int a1 = a0 + 64;

    for (int k0 = 0; k0 < SEQ; k0 += 64) {
        bf16x8 kf[4], vf[4];
        #pragma unroll
        for (int c = 0; c < 4; ++c)
            kf[c] = *(const bf16x8*)&Kh[(size_t)(k0 + c * 16 + lo) * 32 + g * 8];
        vf[0] = *(const bf16x8*)&Vh[(size_t)lo * SEQ + k0 + g * 8];
        vf[1] = *(const bf16x8*)&Vh[(size_t)(16 + lo) * SEQ + k0 + g * 8];
        vf[2] = *(const bf16x8*)&Vh[(size_t)lo * SEQ + k0 + 32 + g * 8];
        vf[3] = *(const bf16x8*)&Vh[(size_t)(16 + lo) * SEQ + k0 + 32 + g * 8];

        f32x4 cb[4];
        #pragma unroll
        for (int c = 0; c < 4; ++c)
            cb[c] = *(const f32x4*)&bias_s[k0 + c * 16 + 4 * g];

        #pragma unroll
        for (int i = 0; i < 2; ++i) {
            // ---- QK^T: 4 independent MFMAs, 64 keys ----
            f32x4 s[4];
            __builtin_amdgcn_s_setprio(1);
            #pragma unroll
            for (int c = 0; c < 4; ++c)
                s[c] = __builtin_amdgcn_mfma_f32_16x16x32_bf16(
                    kf[c], qf[i], cb[c], 0, 0, 0);
            __builtin_amdgcn_s_setprio(0);

            // ---- max over 16 regs + 2 cross-lane ----
            float tm = s[0][0];
            #pragma unroll
            for (int c = 0; c < 4; ++c)
                #pragma unroll
                for (int r = 0; r < 4; ++r) tm = fmaxf(tm, s[c][r]);
            tm = fmaxf(tm, __shfl_xor(tm, 16));
            tm = fmaxf(tm, __shfl_xor(tm, 32));

            // ---- defer-max (THR=0: exact) ----
            if (__any(tm > m[i])) {
                float nm  = fmaxf(m[i], tm);
                float fac = exp2f(m[i] - nm);
                m[i] = nm;
                l[i] *= fac;
                #pragma unroll
                for (int hf = 0; hf < 2; ++hf)
                    #pragma unroll
                    for (int r = 0; r < 4; ++r) acc[i][hf][r] *= fac;
            }

            // ---- P = exp2(s - m), row-sum, pack to bf16 words ----
            float p[16];
            float tl = 0.f;
            #pragma unroll
            for (int c = 0; c < 4; ++c)
                #pragma unroll
                for (int r = 0; r < 4; ++r) {
                    p[c * 4 + r] = exp2f(s[c][r] - m[i]);
                    tl += p[c * 4 + r];
                }
            tl += __shfl_xor(tl, 16);
            tl += __shfl_xor(tl, 32);
            l[i] += tl;

            unsigned wA[4], wB[4];
            #pragma unroll
            for (int c = 0; c < 4; ++c) {
                asm("v_cvt_pk_bf16_f32 %0, %1, %2"
                    : "=v"(wA[c]) : "v"(p[c * 4 + 0]), "v"(p[c * 4 + 1]));
                asm("v_cvt_pk_bf16_f32 %0, %1, %2"
                    : "=v"(wB[c]) : "v"(p[c * 4 + 2]), "v"(p[c * 4 + 3]));
            }

            // ---- PV per 32-key chunk ----
            #pragma unroll
            for (int kc = 0; kc < 2; ++kc) {
                const int c0 = 2 * kc, c1 = 2 * kc + 1;
                int x0 = __builtin_amdgcn_ds_bpermute(a0, (int)wA[c0]);
                int y0 = __builtin_amdgcn_ds_bpermute(a0, (int)wA[c1]);
                int x1 = __builtin_amdgcn_ds_bpermute(a0, (int)wB[c0]);
                int y1 = __builtin_amdgcn_ds_bpermute(a0, (int)wB[c1]);
                int x2 = __builtin_amdgcn_ds_bpermute(a1, (int)wA[c0]);
                int y2 = __builtin_amdgcn_ds_bpermute(a1, (int)wA[c1]);
                int x3 = __builtin_amdgcn_ds_bpermute(a1, (int)wB[c0]);
                int y3 = __builtin_amdgcn_ds_bpermute(a1, (int)wB[c1]);
                const bool hi2 = g >= 2;
                union { int u[4]; bf16x8 v; } pf;
                pf.u[0] = hi2 ? y0 : x0;
                pf.u[1] = hi2 ? y1 : x1;
                pf.u[2] = hi2 ? y2 : x2;
                pf.u[3] = hi2 ? y3 : x3;

                __builtin_amdgcn_s_setprio(1);
                acc[i][0] = __builtin_amdgcn_mfma_f32_16x16x32_bf16(
                    vf[2 * kc + 0], pf.v, acc[i][0], 0, 0, 0);
                acc[i][1] = __builtin_amdgcn_mfma_f32_16x16x32_bf16(
                    vf[2 * kc + 1], pf.v, acc[i][1], 0, 0, 0);
                __builtin_amdgcn_s_setprio(0);
            }
        }
    }

    // epilogue: normalize, transpose O^T -> O via per-wave LDS tile, store
    #pragma unroll
    for (int i = 0; i < 2; ++i) {
        float inv = (l[i] > 0.f) ? 1.0f / l[i] : 0.f;
        #pragma unroll
        for (int hf = 0; hf < 2; ++hf)
            #pragma unroll
            for (int r = 0; r < 4; ++r)
                T[wv][hf * 16 + g * 4 + r][lo] = acc[i][hf][r] * inv;
        __syncthreads();
        #pragma unroll
        for (int p = 0; p < 2; ++p) {
            int row = p * 8 + (lane >> 3);
            int d4  = (lane & 7) * 4;
            float4 ov;
            ov.x = T[wv][d4 + 0][row];
            ov.y = T[wv][d4 + 1][row];
            ov.z = T[wv][d4 + 2][row];
            ov.w = T[wv][d4 + 3][row];
            *(float4*)&O[(size_t)(bb * SEQ + qt + i * 16 + row) * DIM + hh * 32 + d4] = ov;
        }
        __syncthreads();
    }
}

// ---------------------------------------------------------------------------
// Fused residual + LayerNorm, optional bf16 secondary output.
// ---------------------------------------------------------------------------
__global__ __launch_bounds__(256) void ln_kernel(
    const float* __restrict__ X, const float* __restrict__ R,
    const float* __restrict__ gam, const float* __restrict__ bet,
    float* __restrict__ Y, unsigned short* __restrict__ Yb)
{
    const int row = blockIdx.x;
    const int t   = threadIdx.x;
    __shared__ float wsum[4];
    __shared__ float mu_s, rs_s;

    float v = X[(size_t)row * DIM + t] + R[(size_t)row * DIM + t];

    float s = v;
    #pragma unroll
    for (int off = 1; off < 64; off <<= 1) s += __shfl_xor(s, off);
    const int w = t >> 6, lane = t & 63;
    if (lane == 0) wsum[w] = s;
    __syncthreads();
    if (t == 0) mu_s = (wsum[0] + wsum[1] + wsum[2] + wsum[3]) * (1.f / 256.f);
    __syncthreads();
    const float mu = mu_s;
    const float d  = v - mu;

    float s2 = d * d;
    #pragma unroll
    for (int off = 1; off < 64; off <<= 1) s2 += __shfl_xor(s2, off);
    if (lane == 0) wsum[w] = s2;
    __syncthreads();
    if (t == 0)
        rs_s = rsqrtf((wsum[0] + wsum[1] + wsum[2] + wsum[3]) * (1.f / 256.f) + 1e-5f);
    __syncthreads();

    float y = d * rs_s * gam[t] + bet[t];
    Y[(size_t)row * DIM + t] = y;
    if (Yb) Yb[(size_t)row * DIM + t] = (unsigned short)bf16rne(y);
}

// ---------------------------------------------------------------------------
extern "C" void kernel_launch(void* const* d_in, const int* in_sizes, int n_in,
                              void* d_out, int out_size, void* d_ws, size_t ws_size,
                              hipStream_t stream)
{
    const float* x    = (const float*)d_in[0];
    const float* pos  = (const float*)d_in[1];
    const int*   mask = (const int*)d_in[2];
    const float* Wqkv = (const float*)d_in[3];
    const float* bqkv = (const float*)d_in[4];
    const float* Wpos = (const float*)d_in[5];
    const float* bpos = (const float*)d_in[6];
    const float* ln1g = (const float*)d_in[7];
    const float* ln1b = (const float*)d_in[8];
    const float* W1   = (const float*)d_in[9];
    const float* b1   = (const float*)d_in[10];
    const float* W2   = (const float*)d_in[11];
    const float* b2   = (const float*)d_in[12];
    const float* ln2g = (const float*)d_in[13];
    const float* ln2b = (const float*)d_in[14];
    float* out = (float*)d_out;

    // Workspace layout (90 MB), regions reused by lifetime (see round-3 map)
    char* base = (char*)d_ws;
    const size_t MB = 1024 * 1024;
    const size_t SZ = (size_t)MROWS * DIM;           // 4,194,304 elements
    float*          qp   = (float*)(base + 0);
    float*          kp   = (float*)(base + 16 * MB);
    float*          ao   = (float*)(base + 0);
    unsigned short* mid  = (unsigned short*)(base + 0);
    unsigned short* xb   = (unsigned short*)(base + 32 * MB);
    unsigned short* hb   = (unsigned short*)(base + 32 * MB);
    unsigned short* posb = (unsigned short*)(base + 40 * MB);
    float*          hbuf = (float*)(base + 40 * MB);
    unsigned short* qb   = (unsigned short*)(base + 56 * MB);
    unsigned short* kb   = (unsigned short*)(base + 64 * MB);
    unsigned short* vb   = (unsigned short*)(base + 72 * MB);
    unsigned short* vt   = (unsigned short*)(base + 80 * MB);
    unsigned short* wq   = (unsigned short*)(base + 88 * MB);   // [768,256]
    unsigned short* wp   = wq + 768 * 256;                      // [512,512]
    unsigned short* w1   = wp + 512 * 512;                      // [1024,256]
    unsigned short* w2   = w1 + 1024 * 256;                     // [256,1024]
    float*          f2   = out;

    dim3 blk(256);

    // s1) activation converts
    conv_kernel<<<dim3((SZ / 8) / 256), blk, 0, stream>>>(x, xb, SZ / 8);
    conv_kernel<<<dim3((2 * SZ / 8) / 256), blk, 0, stream>>>(pos, posb, 2 * SZ / 8);
    // s2) weight transpose+convert
    wtrans_kernel<<<dim3(768 / 32, 256 / 32), blk, 0, stream>>>(Wqkv, wq, 256, 768);
    wtrans_kernel<<<dim3(512 / 32, 512 / 32), blk, 0, stream>>>(Wpos, wp, 512, 512);
    wtrans_kernel<<<dim3(1024 / 32, 256 / 32), blk, 0, stream>>>(W1, w1, 256, 1024);
    wtrans_kernel<<<dim3(256 / 32, 1024 / 32), blk, 0, stream>>>(W2, w2, 1024, 256);
    // s3) pos @ Wpos + bpos -> fp32 qp/kp scatter
    mgemm_kernel<3><<<dim3(512 / 128, MROWS / 128), blk, 0, stream>>>(
        posb, wp, bpos, nullptr, nullptr, MROWS, 512, 512,
        nullptr, nullptr, qp, kp, nullptr, nullptr, nullptr);
    // s4) x @ Wqkv + bqkv -> q (pre-scaled bf16), k, v
    mgemm_kernel<2><<<dim3(768 / 128, MROWS / 128), blk, 0, stream>>>(
        xb, wq, bqkv, nullptr, nullptr, MROWS, 256, 768,
        qp, kp, nullptr, nullptr, qb, kb, vb);
    // s5) V transpose
    vtrans_kernel<<<dim3(2048), blk, 0, stream>>>(vb, vt);
    // s6) attention -> ao
    attn_kernel<<<dim3(BATCH * NHEAD * (SEQ / 128)), blk, 0, stream>>>(
        qb, kb, vt, mask, ao);
    // s7) h = LN(x + ao) -> hbuf fp32 + hb bf16
    ln_kernel<<<dim3(MROWS), blk, 0, stream>>>(x, ao, ln1g, ln1b, hbuf, hb);
    // s8) relu(h @ W1 + b1) -> mid bf16
    mgemm_kernel<1><<<dim3(1024 / 128, MROWS / 128), blk, 0, stream>>>(
        hb, w1, b1, nullptr, mid, MROWS, 256, 1024,
        nullptr, nullptr, nullptr, nullptr, nullptr, nullptr, nullptr);
    // s9) mid @ W2 + b2 -> f2 (= d_out)
    mgemm_kernel<0><<<dim3(256 / 128, MROWS / 128), blk, 0, stream>>>(
        mid, w2, b2, f2, nullptr, MROWS, 1024, 256,
        nullptr, nullptr, nullptr, nullptr, nullptr, nullptr, nullptr);
    // s10) out = LN(h + ffn), in-place on d_out
    ln_kernel<<<dim3(MROWS), blk, 0, stream>>>(hbuf, f2, ln2g, ln2b, out, nullptr);
}